// Round 8
// baseline (43.611 us; speedup 1.0000x reference)
//
#include <hip/hip_runtime.h>
#include <hip/hip_bf16.h>

typedef __attribute__((ext_vector_type(8))) short bf16x8;
typedef __attribute__((ext_vector_type(4))) float f32x4;

#define N_PTS  500000
#define DIM    64
#define NCLUST 128
#define TILES  (N_PTS / 16)    // 31250, exact
#define NBLK1  1024            // 4 blocks/CU resident at ~115 VGPR, 17KB LDS
#define PSTRIDE (NBLK1 * 2)    // 2048 tile-streams (2 wave-pairs per block)
#define LOG2E  1.44269504088896f
#define LN2    0.69314718055994f

static __device__ __forceinline__ unsigned f2bf(float x) {
    union { float f; unsigned u; } un; un.f = x;
    unsigned u = un.u;
    u += 0x7fffu + ((u >> 16) & 1u);   // RNE
    return u >> 16;
}

static __device__ __forceinline__ float sq4(float4 v) {
    return v.x*v.x + v.y*v.y + v.z*v.z + v.w*v.w;
}

static __device__ __forceinline__ bf16x8 pack8(float4 a, float4 b) {
    union { bf16x8 v; __hip_bfloat162 h[4]; } u;
    u.h[0] = __float22bfloat162_rn(make_float2(a.x, a.y));
    u.h[1] = __float22bfloat162_rn(make_float2(a.z, a.w));
    u.h[2] = __float22bfloat162_rn(make_float2(b.x, b.y));
    u.h[3] = __float22bfloat162_rn(make_float2(b.z, b.w));
    return u.v;
}

static __device__ __forceinline__ float max3f(float a, float b, float c) {
    return fmaxf(fmaxf(a, b), c);   // clang fuses to v_max3_f32
}

// Pass 1: each wave = 16 points x 64 clusters (half). Wave pairs within a
// block share a tile (duplicate loads -> L1). Partial (max, sumexp) -> ws.
__global__ __launch_bounds__(256) void kmeans_part1(
    const float* __restrict__ X, const float* __restrict__ centers,
    const float* __restrict__ vars_, const float* __restrict__ prs,
    float2* __restrict__ ws)
{
    __shared__ unsigned short sC[NCLUST * DIM];   // 16 KB, swizzled scaled centers
    __shared__ float sAf[NCLUST];  // a_j = -0.5/var_j*log2e
    __shared__ float sBf[NCLUST];  // b_j = a_j*||c_j||^2 + log2(prs_j)

    const int tid = threadIdx.x;
    {   // prologue: 2 threads per cluster row
        const int j = tid >> 1, h = tid & 1;
        const float inv = 1.0f / vars_[j];
        const float cscale = inv * LOG2E;
        float c2p = 0.0f;
        #pragma unroll
        for (int k = 32*h; k < 32*h + 32; k += 4) {
            float4 c = *(const float4*)(centers + j*DIM + k);
            c2p = fmaf(c.x, c.x, fmaf(c.y, c.y, fmaf(c.z, c.z, fmaf(c.w, c.w, c2p))));
            const int base = j*64 + (((k >> 3) ^ (j & 7)) << 3) + (k & 7);
            sC[base+0] = (unsigned short)f2bf(c.x * cscale);
            sC[base+1] = (unsigned short)f2bf(c.y * cscale);
            sC[base+2] = (unsigned short)f2bf(c.z * cscale);
            sC[base+3] = (unsigned short)f2bf(c.w * cscale);
        }
        c2p += __shfl_xor(c2p, 1);
        if (h == 0) {
            const float a = -0.5f * inv * LOG2E;
            sAf[j] = a;
            sBf[j] = fmaf(a, c2p, __log2f(prs[j]));
        }
    }
    __syncthreads();

    const int lane = tid & 63;
    const int wid  = tid >> 6;
    const int g    = lane >> 4;     // k-chunk group (0..3)
    const int r    = lane & 15;     // point (B col) / cluster-row (A row)
    const bool g0  = (g == 0);
    const int h    = wid & 1;       // cluster half (0: 0-63, 1: 64-127)
    const int pairIdx = wid >> 1;   // tile stream within block

    // Half-fragments in registers: t' = 4h + t, t = 0..3  (32 VGPR)
    const unsigned co1 = (unsigned)r*64 + ((unsigned)(g ^ (r & 7)) << 3);
    const unsigned co2 = co1 ^ 32;
    bf16x8 Cf0[4], Cf1[4];
    #pragma unroll
    for (int t = 0; t < 4; ++t) {
        const int tt = 4*h + t;
        Cf0[t] = *(const bf16x8*)&sC[tt*1024 + co1];
        Cf1[t] = *(const bf16x8*)&sC[tt*1024 + co2];
    }

    // acc-init A-operand for the half (16 VGPR):
    //   k-slots [a_hi, a_hi, a_lo, b_hi, b_lo, 0,0,0] on g==0 lanes.
    bf16x8 A3[4];
    #pragma unroll
    for (int t = 0; t < 4; ++t) {
        const float a = sAf[16*(4*h + t) + r];
        const float b = sBf[16*(4*h + t) + r];
        const unsigned ah = f2bf(a);
        const unsigned al = f2bf(a - __uint_as_float(ah << 16));
        const unsigned bh = f2bf(b);
        const unsigned bl = f2bf(b - __uint_as_float(bh << 16));
        union { bf16x8 v; unsigned w[4]; } u;
        u.w[0] = g0 ? (ah | (ah << 16)) : 0u;
        u.w[1] = g0 ? (al | (bh << 16)) : 0u;
        u.w[2] = g0 ? bl : 0u;
        u.w[3] = 0u;
        A3[t] = u.v;
    }

    int tile = blockIdx.x*2 + pairIdx;
    const size_t lane_off = (size_t)r * DIM + 8*g;

    // depth-1 prefetch (R4 style)
    float4 c0, c1, c2v, c3, n0{}, n1{}, n2{}, n3{};
    {
        const float* p = X + (size_t)tile*16*DIM + lane_off;
        c0 = *(const float4*)(p);    c1 = *(const float4*)(p+4);
        c2v= *(const float4*)(p+32); c3 = *(const float4*)(p+36);
    }
    int nt = tile + PSTRIDE;

    for (;;) {
        if (nt < TILES) {
            const float* p = X + (size_t)nt*16*DIM + lane_off;
            n0 = *(const float4*)(p);    n1 = *(const float4*)(p+4);
            n2 = *(const float4*)(p+32); n3 = *(const float4*)(p+36);
        }

        float ss = sq4(c0) + sq4(c1) + sq4(c2v) + sq4(c3);
        ss += __shfl_xor(ss, 16);
        ss += __shfl_xor(ss, 32);

        bf16x8 B0 = pack8(c0, c1);
        bf16x8 B1 = pack8(c2v, c3);

        // B3: [s_hi, s_lo, s_hi, 1, 1, 0,0,0] on g==0 lanes
        const unsigned sh = f2bf(ss);
        const unsigned sl = f2bf(ss - __uint_as_float(sh << 16));
        union { bf16x8 v; unsigned w[4]; } ub;
        ub.w[0] = g0 ? (sh | (sl << 16)) : 0u;
        ub.w[1] = g0 ? (sh | 0x3F800000u) : 0u;
        ub.w[2] = g0 ? 0x3F80u : 0u;
        ub.w[3] = 0u;
        const bf16x8 B3 = ub.v;

        // acc[t][q] = logit~ (log2 domain) of cluster 16*(4h+t)+4g+q, point r
        f32x4 acc[4];
        #pragma unroll
        for (int t = 0; t < 4; ++t) {
            f32x4 z = (f32x4){0.f, 0.f, 0.f, 0.f};
            z = __builtin_amdgcn_mfma_f32_16x16x32_bf16(A3[t], B3, z, 0, 0, 0);
            z = __builtin_amdgcn_mfma_f32_16x16x32_bf16(Cf1[t], B1, z, 0, 0, 0);
            acc[t] = __builtin_amdgcn_mfma_f32_16x16x32_bf16(Cf0[t], B0, z, 0, 0, 0);
        }

        // lane-local max over 16, then combine 4 g-lanes (2 shuffles)
        float m0 = max3f(acc[0][0], acc[1][0], acc[2][0]);
        float m1 = max3f(acc[0][1], acc[1][1], acc[2][1]);
        float m2 = max3f(acc[0][2], acc[1][2], acc[2][2]);
        float m3 = max3f(acc[0][3], acc[1][3], acc[2][3]);
        m0 = fmaxf(m0, acc[3][0]);
        m1 = fmaxf(m1, acc[3][1]);
        m2 = fmaxf(m2, acc[3][2]);
        m3 = fmaxf(m3, acc[3][3]);
        float mw = fmaxf(max3f(m0, m1, m2), m3);
        float mx = fmaxf(mw, __shfl_xor(mw, 16));
        mx = fmaxf(mx, __shfl_xor(mx, 32));

        float s0 = 0.f, s1 = 0.f, s2 = 0.f, s3 = 0.f;
        #pragma unroll
        for (int t = 0; t < 4; ++t) {
            s0 += __builtin_amdgcn_exp2f(acc[t][0] - mx);
            s1 += __builtin_amdgcn_exp2f(acc[t][1] - mx);
            s2 += __builtin_amdgcn_exp2f(acc[t][2] - mx);
            s3 += __builtin_amdgcn_exp2f(acc[t][3] - mx);
        }
        float sm = (s0 + s1) + (s2 + s3);
        sm += __shfl_xor(sm, 16);
        sm += __shfl_xor(sm, 32);

        if (lane < 16) {
            ws[(size_t)(tile*16 + lane)*2 + h] = make_float2(mx, sm);
        }

        if (nt >= TILES) break;
        tile = nt; nt += PSTRIDE;
        c0 = n0; c1 = n1; c2v = n2; c3 = n3;
    }
}

// Pass 2: LSE-combine the two halves per point.
__global__ __launch_bounds__(256) void kmeans_part2(
    const float2* __restrict__ ws, const float* __restrict__ threshold,
    float* __restrict__ out)
{
    const int p = blockIdx.x * 256 + threadIdx.x;
    if (p >= N_PTS) return;
    const float4 v = ((const float4*)ws)[p];   // (m0, s0, m1, s1)
    const float m = fmaxf(v.x, v.z);
    const float s = v.y * __builtin_amdgcn_exp2f(v.x - m)
                  + v.w * __builtin_amdgcn_exp2f(v.z - m);
    out[p] = fmaf(m + __builtin_amdgcn_logf(s), LN2, -threshold[0]);
}

extern "C" void kernel_launch(void* const* d_in, const int* in_sizes, int n_in,
                              void* d_out, int out_size, void* d_ws, size_t ws_size,
                              hipStream_t stream) {
    const float* X         = (const float*)d_in[0];
    const float* centers   = (const float*)d_in[1];
    const float* vars_     = (const float*)d_in[2];
    const float* prs       = (const float*)d_in[3];
    const float* threshold = (const float*)d_in[4];
    float* out = (float*)d_out;
    float2* ws = (float2*)d_ws;
    (void)in_sizes; (void)n_in; (void)out_size; (void)ws_size;

    kmeans_part1<<<NBLK1, 256, 0, stream>>>(X, centers, vars_, prs, ws);
    kmeans_part2<<<(N_PTS + 255)/256, 256, 0, stream>>>(ws, threshold, out);
}

// Round 9
// 38.020 us; speedup vs baseline: 1.1471x; 1.1471x over previous
//
#include <hip/hip_runtime.h>
#include <hip/hip_bf16.h>

typedef __attribute__((ext_vector_type(8))) short bf16x8;
typedef __attribute__((ext_vector_type(4))) float f32x4;
typedef __attribute__((ext_vector_type(8))) _Float16 h8;
typedef __attribute__((ext_vector_type(2))) _Float16 h2;

#define N_PTS  500000
#define DIM    64
#define NCLUST 128
#define TILES  (N_PTS / 16)   // 31250, exact
#define NBLK   768            // 3 blocks/CU resident at <=170 VGPR
#define LOG2E  1.44269504088896f
#define LN2    0.69314718055994f

static __device__ __forceinline__ unsigned f2bf(float x) {
    union { float f; unsigned u; } un; un.f = x;
    unsigned u = un.u;
    u += 0x7fffu + ((u >> 16) & 1u);   // RNE
    return u >> 16;
}

// non-temporal 16B vector load (global_load_dwordx4 ... nt)
static __device__ __forceinline__ f32x4 ntld(const float* p) {
    return __builtin_nontemporal_load((const f32x4*)p);
}

static __device__ __forceinline__ float sq4(f32x4 v) {
    return v[0]*v[0] + v[1]*v[1] + v[2]*v[2] + v[3]*v[3];
}

static __device__ __forceinline__ bf16x8 pack8(f32x4 a, f32x4 b) {
    union { bf16x8 v; __hip_bfloat162 h[4]; } u;
    u.h[0] = __float22bfloat162_rn(make_float2(a[0], a[1]));
    u.h[1] = __float22bfloat162_rn(make_float2(a[2], a[3]));
    u.h[2] = __float22bfloat162_rn(make_float2(b[0], b[1]));
    u.h[3] = __float22bfloat162_rn(make_float2(b[2], b[3]));
    return u.v;
}

__global__ __launch_bounds__(256, 3) void kmeans_lse_kernel(
    const float* __restrict__ X, const float* __restrict__ centers,
    const float* __restrict__ vars_, const float* __restrict__ prs,
    const float* __restrict__ threshold, float* __restrict__ out)
{
    // Scaled centers c'_j = c_j/var_j*log2e as bf16, XOR-slot-swizzled:
    //   element (j,k) at ushort index j*64 + (((k>>3) ^ (j&7))<<3) + (k&7)
    __shared__ unsigned short sC[NCLUST * DIM];       // 16 KB (used pre-loop only)
    // Per-cluster LSE constants as f16, 16B block per (t,g) quad:
    //   block (j>>2): halfs [a(4j..4j+3) | b(4j..4j+3)]
    //   a_j = -0.5/var_j*log2e,  b_j = a_j*||c_j||^2 + log2(prs_j)
    __shared__ __align__(16) _Float16 sABh[NCLUST * 2];  // 512 B

    const int tid = threadIdx.x;
    {   // init: 2 threads per cluster row (halves)
        const int j = tid >> 1, h = tid & 1;
        const float inv = 1.0f / vars_[j];
        const float cscale = inv * LOG2E;
        float c2p = 0.0f;
        #pragma unroll
        for (int k = 32*h; k < 32*h + 32; k += 4) {
            float4 c = *(const float4*)(centers + j*DIM + k);
            c2p = fmaf(c.x, c.x, fmaf(c.y, c.y, fmaf(c.z, c.z, fmaf(c.w, c.w, c2p))));
            const int base = j*64 + (((k >> 3) ^ (j & 7)) << 3) + (k & 7);
            sC[base+0] = (unsigned short)f2bf(c.x * cscale);
            sC[base+1] = (unsigned short)f2bf(c.y * cscale);
            sC[base+2] = (unsigned short)f2bf(c.z * cscale);
            sC[base+3] = (unsigned short)f2bf(c.w * cscale);
        }
        c2p += __shfl_xor(c2p, 1);   // partner half of same row
        if (h == 0) {
            const float a = -0.5f * inv * LOG2E;
            const float b = fmaf(a, c2p, __log2f(prs[j]));
            sABh[(j>>2)*8 + (j&3)]     = (_Float16)a;
            sABh[(j>>2)*8 + 4 + (j&3)] = (_Float16)b;
        }
    }
    __syncthreads();

    const int lane = tid & 63;
    const int wid  = tid >> 6;
    const int g    = lane >> 4;   // k-chunk group (0..3)
    const int r    = lane & 15;   // point-in-tile (B col) / cluster-row (A row)

    // Center fragments -> registers for the whole loop (64 VGPRs).
    const unsigned co1 = (unsigned)r*64 + ((unsigned)(g ^ (r & 7)) << 3);  // chunk g
    const unsigned co2 = co1 ^ 32;                                         // chunk 4+g
    bf16x8 Cf0[8], Cf1[8];
    #pragma unroll
    for (int t = 0; t < 8; ++t) {
        Cf0[t] = *(const bf16x8*)&sC[t*1024 + co1];
        Cf1[t] = *(const bf16x8*)&sC[t*1024 + co2];
    }

    const float thr = threshold[0];
    const int S = NBLK * 4;        // grid stride in tiles (3072)
    int tile = blockIdx.x*4 + wid;
    const size_t lane_off = (size_t)r * DIM + 8*g;

    const float* pc = X + (size_t)tile*16*DIM + lane_off;
    f32x4 c0 = ntld(pc),    c1 = ntld(pc+4),
          c2v= ntld(pc+32), c3 = ntld(pc+36);
    f32x4 n0{}, n1{}, n2{}, n3{};
    int nt = tile + S;

    for (;;) {
        if (nt < TILES) {          // depth-1 prefetch (wave-uniform branch)
            const float* pn = X + (size_t)nt*16*DIM + lane_off;
            n0 = ntld(pn);    n1 = ntld(pn+4);
            n2 = ntld(pn+32); n3 = ntld(pn+36);
        }

        // full ||x_r||^2 into every lane (2 shuffles)
        float ss = sq4(c0) + sq4(c1) + sq4(c2v) + sq4(c3);
        ss += __shfl_xor(ss, 16);
        ss += __shfl_xor(ss, 32);

        bf16x8 B0 = pack8(c0, c1);    // points = B operand, k-chunks g / 4+g
        bf16x8 B1 = pack8(c2v, c3);

        const h2 ss2 = {(_Float16)ss, (_Float16)ss};

        // acc[t][q] = logit~ of cluster 16t+4g+q for point r (log2 domain)
        f32x4 acc[8];
        #pragma unroll
        for (int t = 0; t < 8; ++t) {
            // one broadcast b128: [a-quad | b-quad] as f16 (volatile: keep in LDS)
            h8 ab = *(const volatile h8*)&sABh[t*32 + g*8];
            h2 i01 = __builtin_shufflevector(ab, ab, 0, 1) * ss2
                   + __builtin_shufflevector(ab, ab, 4, 5);
            h2 i23 = __builtin_shufflevector(ab, ab, 2, 3) * ss2
                   + __builtin_shufflevector(ab, ab, 6, 7);
            acc[t][0] = (float)i01[0]; acc[t][1] = (float)i01[1];
            acc[t][2] = (float)i23[0]; acc[t][3] = (float)i23[1];
            acc[t] = __builtin_amdgcn_mfma_f32_16x16x32_bf16(Cf0[t], B0, acc[t], 0, 0, 0);
            acc[t] = __builtin_amdgcn_mfma_f32_16x16x32_bf16(Cf1[t], B1, acc[t], 0, 0, 0);
        }

        // lane-local max over 32 clusters, then combine the 4 g-lanes
        float mx = acc[0][0];
        #pragma unroll
        for (int t = 0; t < 8; ++t)
            #pragma unroll
            for (int q = 0; q < 4; ++q) mx = fmaxf(mx, acc[t][q]);
        mx = fmaxf(mx, __shfl_xor(mx, 16));
        mx = fmaxf(mx, __shfl_xor(mx, 32));

        // sum of exp2 with 4 independent partials (shorter dep chains)
        float s0 = 0.f, s1 = 0.f, s2 = 0.f, s3 = 0.f;
        #pragma unroll
        for (int t = 0; t < 8; ++t) {
            s0 += __builtin_amdgcn_exp2f(acc[t][0] - mx);
            s1 += __builtin_amdgcn_exp2f(acc[t][1] - mx);
            s2 += __builtin_amdgcn_exp2f(acc[t][2] - mx);
            s3 += __builtin_amdgcn_exp2f(acc[t][3] - mx);
        }
        float sm = (s0 + s1) + (s2 + s3);
        sm += __shfl_xor(sm, 16);
        sm += __shfl_xor(sm, 32);

        if (lane < 16) {
            out[tile*16 + lane] =
                fmaf(mx + __builtin_amdgcn_logf(sm), LN2, -thr);  // v_log_f32 = log2
        }

        if (nt >= TILES) break;
        tile = nt; nt += S;
        c0 = n0; c1 = n1; c2v = n2; c3 = n3;
    }
}

extern "C" void kernel_launch(void* const* d_in, const int* in_sizes, int n_in,
                              void* d_out, int out_size, void* d_ws, size_t ws_size,
                              hipStream_t stream) {
    const float* X         = (const float*)d_in[0];
    const float* centers   = (const float*)d_in[1];
    const float* vars_     = (const float*)d_in[2];
    const float* prs       = (const float*)d_in[3];
    const float* threshold = (const float*)d_in[4];
    float* out = (float*)d_out;
    (void)in_sizes; (void)n_in; (void)out_size; (void)d_ws; (void)ws_size;

    kmeans_lse_kernel<<<NBLK, 256, 0, stream>>>(X, centers, vars_, prs, threshold, out);
}

// Round 10
// 33.485 us; speedup vs baseline: 1.3024x; 1.1354x over previous
//
#include <hip/hip_runtime.h>
#include <hip/hip_bf16.h>

typedef __attribute__((ext_vector_type(8))) short bf16x8;
typedef __attribute__((ext_vector_type(4))) float f32x4;
typedef __attribute__((ext_vector_type(8))) _Float16 h8;
typedef __attribute__((ext_vector_type(2))) _Float16 h2;

#define N_PTS  500000
#define DIM    64
#define NCLUST 128
#define TILES  (N_PTS / 16)   // 31250, exact
#define NBLK   768            // 3 blocks/CU resident at <=170 VGPR
#define LOG2E  1.44269504088896f
#define LN2    0.69314718055994f

static __device__ __forceinline__ unsigned f2bf(float x) {
    union { float f; unsigned u; } un; un.f = x;
    unsigned u = un.u;
    u += 0x7fffu + ((u >> 16) & 1u);   // RNE
    return u >> 16;
}

static __device__ __forceinline__ float sq4(f32x4 v) {
    return v[0]*v[0] + v[1]*v[1] + v[2]*v[2] + v[3]*v[3];
}

static __device__ __forceinline__ bf16x8 pack8(f32x4 a, f32x4 b) {
    union { bf16x8 v; __hip_bfloat162 h[4]; } u;
    u.h[0] = __float22bfloat162_rn(make_float2(a[0], a[1]));
    u.h[1] = __float22bfloat162_rn(make_float2(a[2], a[3]));
    u.h[2] = __float22bfloat162_rn(make_float2(b[0], b[1]));
    u.h[3] = __float22bfloat162_rn(make_float2(b[2], b[3]));
    return u.v;
}

__global__ __launch_bounds__(256, 3) void kmeans_lse_kernel(
    const float* __restrict__ X, const float* __restrict__ centers,
    const float* __restrict__ vars_, const float* __restrict__ prs,
    const float* __restrict__ threshold, float* __restrict__ out)
{
    // Scaled centers c'_j = c_j/var_j*log2e as bf16, XOR-slot-swizzled (prologue only):
    //   element (j,k) at ushort index j*64 + (((k>>3) ^ (j&7))<<3) + (k&7)
    __shared__ unsigned short sC[NCLUST * DIM];          // 16 KB
    // Per-cluster LSE constants as f16: block (j>>2): halfs [a-quad | b-quad]
    __shared__ __align__(16) _Float16 sABh[NCLUST * 2];  // 512 B
    // Per-wave 4 KB transpose-staging buffer, XOR-swizzled (byte ^= (point&7)<<4)
    __shared__ __align__(16) float sStage[4][1024];      // 16 KB

    const int tid = threadIdx.x;
    {   // prologue: 2 threads per cluster row (halves)
        const int j = tid >> 1, h = tid & 1;
        const float inv = 1.0f / vars_[j];
        const float cscale = inv * LOG2E;
        float c2p = 0.0f;
        #pragma unroll
        for (int k = 32*h; k < 32*h + 32; k += 4) {
            float4 c = *(const float4*)(centers + j*DIM + k);
            c2p = fmaf(c.x, c.x, fmaf(c.y, c.y, fmaf(c.z, c.z, fmaf(c.w, c.w, c2p))));
            const int base = j*64 + (((k >> 3) ^ (j & 7)) << 3) + (k & 7);
            sC[base+0] = (unsigned short)f2bf(c.x * cscale);
            sC[base+1] = (unsigned short)f2bf(c.y * cscale);
            sC[base+2] = (unsigned short)f2bf(c.z * cscale);
            sC[base+3] = (unsigned short)f2bf(c.w * cscale);
        }
        c2p += __shfl_xor(c2p, 1);   // partner half of same row
        if (h == 0) {
            const float a = -0.5f * inv * LOG2E;
            const float b = fmaf(a, c2p, __log2f(prs[j]));
            sABh[(j>>2)*8 + (j&3)]     = (_Float16)a;
            sABh[(j>>2)*8 + 4 + (j&3)] = (_Float16)b;
        }
    }
    __syncthreads();

    const int lane = tid & 63;
    const int wid  = tid >> 6;
    const int g    = lane >> 4;   // k-chunk group (0..3)
    const int r    = lane & 15;   // point-in-tile (B col) / cluster-row (A row)

    // Center fragments -> registers for the whole loop (64 VGPRs).
    const unsigned co1 = (unsigned)r*64 + ((unsigned)(g ^ (r & 7)) << 3);  // chunk g
    const unsigned co2 = co1 ^ 32;                                         // chunk 4+g
    bf16x8 Cf0[8], Cf1[8];
    #pragma unroll
    for (int t = 0; t < 8; ++t) {
        Cf0[t] = *(const bf16x8*)&sC[t*1024 + co1];
        Cf1[t] = *(const bf16x8*)&sC[t*1024 + co2];
    }

    // Loop-invariant staging addresses (bytes into sStage).
    //   store: data of byte-offset d goes to d ^ (((d>>8)&7)<<4)   (point-low3 XOR)
    //   write i: lane l -> 1024*i + 16*l ; (d>>8)&7 = (4i+g)&7
    //   read: lane (g,r) -> point r, k-chunks g / 4+g
    char* sb = (char*)&sStage[0][0];
    const unsigned wbase = (unsigned)wid * 4096u;
    const unsigned wbA = wbase + ((16u*(unsigned)lane) ^ ((unsigned)g << 4));
    const unsigned wbB = wbA ^ 64u;    // writes i=1,3 use ((4+g)&7)<<4 = (g<<4)^64
    const unsigned rb0 = wbase + (((256u*(unsigned)r + 32u*(unsigned)g))
                                  ^ (((unsigned)(r & 7)) << 4));

    const float thr = threshold[0];
    const int S = NBLK * 4;        // grid stride in tiles (3072)
    int tile = blockIdx.x*4 + wid;

    // Fully-coalesced loads: instruction i = contiguous 1KB, lane l <-> bytes l*16.
    const float* pc = X + (size_t)tile*1024 + 4*lane;
    f32x4 c0 = *(const f32x4*)(pc);       f32x4 c1 = *(const f32x4*)(pc + 256);
    f32x4 c2v= *(const f32x4*)(pc + 512); f32x4 c3 = *(const f32x4*)(pc + 768);
    f32x4 n0{}, n1{}, n2{}, n3{};
    int nt = tile + S;

    for (;;) {
        if (nt < TILES) {          // depth-1 prefetch (coalesced)
            const float* pn = X + (size_t)nt*1024 + 4*lane;
            n0 = *(const f32x4*)(pn);       n1 = *(const f32x4*)(pn + 256);
            n2 = *(const f32x4*)(pn + 512); n3 = *(const f32x4*)(pn + 768);
        }

        // stage current tile (linear-lane data) into swizzled LDS
        *(f32x4*)(sb + wbA)        = c0;
        *(f32x4*)(sb + wbB + 1024) = c1;
        *(f32x4*)(sb + wbA + 2048) = c2v;
        *(f32x4*)(sb + wbB + 3072) = c3;

        // transpose-read: lane (g,r) gets point r, k[8g..8g+8) and k[32+8g..+8)
        f32x4 f1a = *(const f32x4*)(sb + rb0);
        f32x4 f1b = *(const f32x4*)(sb + (rb0 ^ 16u));
        f32x4 f2a = *(const f32x4*)(sb + (rb0 ^ 128u));
        f32x4 f2b = *(const f32x4*)(sb + (rb0 ^ 144u));

        // full ||x_r||^2 into every lane (2 shuffles)
        float ss = sq4(f1a) + sq4(f1b) + sq4(f2a) + sq4(f2b);
        ss += __shfl_xor(ss, 16);
        ss += __shfl_xor(ss, 32);

        bf16x8 B0 = pack8(f1a, f1b);    // k-chunk g
        bf16x8 B1 = pack8(f2a, f2b);    // k-chunk 4+g

        const h2 ss2 = {(_Float16)ss, (_Float16)ss};

        // acc[t][q] = logit~ of cluster 16t+4g+q for point r (log2 domain)
        f32x4 acc[8];
        #pragma unroll
        for (int t = 0; t < 8; ++t) {
            h8 ab = *(const volatile h8*)&sABh[t*32 + g*8];
            h2 i01 = __builtin_shufflevector(ab, ab, 0, 1) * ss2
                   + __builtin_shufflevector(ab, ab, 4, 5);
            h2 i23 = __builtin_shufflevector(ab, ab, 2, 3) * ss2
                   + __builtin_shufflevector(ab, ab, 6, 7);
            acc[t][0] = (float)i01[0]; acc[t][1] = (float)i01[1];
            acc[t][2] = (float)i23[0]; acc[t][3] = (float)i23[1];
            acc[t] = __builtin_amdgcn_mfma_f32_16x16x32_bf16(Cf0[t], B0, acc[t], 0, 0, 0);
            acc[t] = __builtin_amdgcn_mfma_f32_16x16x32_bf16(Cf1[t], B1, acc[t], 0, 0, 0);
        }

        // lane-local max over 32 clusters, then combine the 4 g-lanes
        float mx = acc[0][0];
        #pragma unroll
        for (int t = 0; t < 8; ++t)
            #pragma unroll
            for (int q = 0; q < 4; ++q) mx = fmaxf(mx, acc[t][q]);
        mx = fmaxf(mx, __shfl_xor(mx, 16));
        mx = fmaxf(mx, __shfl_xor(mx, 32));

        // sum of exp2 with 4 independent partials
        float s0 = 0.f, s1 = 0.f, s2 = 0.f, s3 = 0.f;
        #pragma unroll
        for (int t = 0; t < 8; ++t) {
            s0 += __builtin_amdgcn_exp2f(acc[t][0] - mx);
            s1 += __builtin_amdgcn_exp2f(acc[t][1] - mx);
            s2 += __builtin_amdgcn_exp2f(acc[t][2] - mx);
            s3 += __builtin_amdgcn_exp2f(acc[t][3] - mx);
        }
        float sm = (s0 + s1) + (s2 + s3);
        sm += __shfl_xor(sm, 16);
        sm += __shfl_xor(sm, 32);

        if (lane < 16) {
            out[tile*16 + lane] =
                fmaf(mx + __builtin_amdgcn_logf(sm), LN2, -thr);  // v_log_f32 = log2
        }

        if (nt >= TILES) break;
        tile = nt; nt += S;
        c0 = n0; c1 = n1; c2v = n2; c3 = n3;
    }
}

extern "C" void kernel_launch(void* const* d_in, const int* in_sizes, int n_in,
                              void* d_out, int out_size, void* d_ws, size_t ws_size,
                              hipStream_t stream) {
    const float* X         = (const float*)d_in[0];
    const float* centers   = (const float*)d_in[1];
    const float* vars_     = (const float*)d_in[2];
    const float* prs       = (const float*)d_in[3];
    const float* threshold = (const float*)d_in[4];
    float* out = (float*)d_out;
    (void)in_sizes; (void)n_in; (void)out_size; (void)d_ws; (void)ws_size;

    kmeans_lse_kernel<<<NBLK, 256, 0, stream>>>(X, centers, vars_, prs, threshold, out);
}